// Round 1
// baseline (401.634 us; speedup 1.0000x reference)
//
#include <hip/hip_runtime.h>

#define BN 32768
#define NB 16
#define NN 2048
#define CC 256

using short8  = __attribute__((ext_vector_type(8))) short;
using floatx4 = __attribute__((ext_vector_type(4))) float;

__device__ __forceinline__ unsigned short f2bf(float f) {
  unsigned u = __builtin_bit_cast(unsigned, f);
  u += 0x7fffu + ((u >> 16) & 1u);
  return (unsigned short)(u >> 16);
}
__device__ __forceinline__ float bf2f(unsigned short h) {
  unsigned u = ((unsigned)h) << 16;
  return __builtin_bit_cast(float, u);
}

// ---------------- LayerNorm: one wave per row, bf16 output ----------------
__global__ __launch_bounds__(256) void ln_kernel(
    const float* __restrict__ x, const float* __restrict__ lw,
    const float* __restrict__ lb, unsigned short* __restrict__ normed) {
  int row  = blockIdx.x * 4 + (threadIdx.x >> 6);
  int lane = threadIdx.x & 63;
  float4 v = ((const float4*)(x + (size_t)row * CC))[lane];
  float s  = v.x + v.y + v.z + v.w;
  float s2 = v.x * v.x + v.y * v.y + v.z * v.z + v.w * v.w;
#pragma unroll
  for (int off = 32; off; off >>= 1) {
    s  += __shfl_xor(s, off);
    s2 += __shfl_xor(s2, off);
  }
  float mu = s * (1.0f / CC);
  float rs = rsqrtf(s2 * (1.0f / CC) - mu * mu + 1e-5f);
  float4 w = ((const float4*)lw)[lane];
  float4 b = ((const float4*)lb)[lane];
  ushort4 o;
  o.x = f2bf((v.x - mu) * rs * w.x + b.x);
  o.y = f2bf((v.y - mu) * rs * w.y + b.y);
  o.z = f2bf((v.z - mu) * rs * w.z + b.z);
  o.w = f2bf((v.w - mu) * rs * w.w + b.w);
  ((ushort4*)(normed + (size_t)row * CC))[lane] = o;
}

// ------------- transpose fp32 KxN weight -> bf16 NxK (row-major) -------------
__global__ void wconv_kernel(const float* __restrict__ src,
                             unsigned short* __restrict__ dst, int K, int N) {
  int idx = blockIdx.x * 256 + threadIdx.x;
  if (idx >= K * N) return;
  int n = idx / K, k = idx - n * K;
  dst[idx] = f2bf(src[(size_t)k * N + n]);
}

// --------- GEMM1: normed @ w_hidden + b, silu, split into v / gate ---------
__global__ __launch_bounds__(256) void gemm_hidden(
    const unsigned short* __restrict__ A, const unsigned short* __restrict__ BT,
    const float* __restrict__ bias,
    unsigned short* __restrict__ vout, unsigned short* __restrict__ gout) {
  int wave = threadIdx.x >> 6, lane = threadIdx.x & 63;
  int m0 = blockIdx.x * 64, n0 = blockIdx.y * 64;
  int m = lane & 15, kb = (lane >> 4) * 8;
  int arow = m0 + wave * 16 + m;
  floatx4 acc[4] = {};
#pragma unroll
  for (int ks = 0; ks < 8; ++ks) {
    short8 a = *(const short8*)(A + (size_t)arow * CC + ks * 32 + kb);
#pragma unroll
    for (int f = 0; f < 4; ++f) {
      short8 bb = *(const short8*)(BT + (size_t)(n0 + f * 16 + m) * CC + ks * 32 + kb);
      acc[f] = __builtin_amdgcn_mfma_f32_16x16x32_bf16(a, bb, acc[f], 0, 0, 0);
    }
  }
  int ob = m0 + wave * 16 + ((lane >> 4) << 2);
#pragma unroll
  for (int f = 0; f < 4; ++f) {
    int col = n0 + f * 16 + m;
    float bv = bias[col];
#pragma unroll
    for (int r = 0; r < 4; ++r) {
      float h = acc[f][r] + bv;
      float sv = h / (1.0f + __expf(-h));
      unsigned short hb = f2bf(sv);
      size_t rr = (size_t)(ob + r) * CC;
      if (col < CC) vout[rr + col] = hb;
      else          gout[rr + (col - CC)] = hb;
    }
  }
}

// ----------- GEMM2: normed @ w_kv -> Z; q = Z*g0+b0, k = Z*g1+b1 -----------
__global__ __launch_bounds__(256) void gemm_kv(
    const unsigned short* __restrict__ A, const unsigned short* __restrict__ BT,
    const float* __restrict__ gamma, const float* __restrict__ beta,
    unsigned short* __restrict__ qout, unsigned short* __restrict__ kout) {
  int wave = threadIdx.x >> 6, lane = threadIdx.x & 63;
  int m0 = blockIdx.x * 64, n0 = blockIdx.y * 64;
  int m = lane & 15, kb = (lane >> 4) * 8;
  int arow = m0 + wave * 16 + m;
  floatx4 acc[4] = {};
#pragma unroll
  for (int ks = 0; ks < 8; ++ks) {
    short8 a = *(const short8*)(A + (size_t)arow * CC + ks * 32 + kb);
#pragma unroll
    for (int f = 0; f < 4; ++f) {
      short8 bb = *(const short8*)(BT + (size_t)(n0 + f * 16 + m) * CC + ks * 32 + kb);
      acc[f] = __builtin_amdgcn_mfma_f32_16x16x32_bf16(a, bb, acc[f], 0, 0, 0);
    }
  }
  int ob = m0 + wave * 16 + ((lane >> 4) << 2);
#pragma unroll
  for (int f = 0; f < 4; ++f) {
    int col = n0 + f * 16 + m;
    float g0 = gamma[col], b0 = beta[col];
    float g1 = gamma[CC + col], b1 = beta[CC + col];
#pragma unroll
    for (int r = 0; r < 4; ++r) {
      float z = acc[f][r];
      size_t rr = (size_t)(ob + r) * CC;
      qout[rr + col] = f2bf(z * g0 + b0);
      kout[rr + col] = f2bf(z * g1 + b1);
    }
  }
}

// ---- fused attention: Vg = (relu(q k^T / n)^2 @ v) * gate, bf16 out ----
__global__ __launch_bounds__(256) void attn_kernel(
    const unsigned short* __restrict__ qg, const unsigned short* __restrict__ kg,
    const unsigned short* __restrict__ vg, const unsigned short* __restrict__ gg,
    unsigned short* __restrict__ og) {
  __shared__ unsigned short Kl[32][264];   // K tile, padded rows (16B-aligned)
  __shared__ unsigned short Vt[256][40];   // V tile transposed, XOR-swizzled j-blocks
  __shared__ unsigned short Pl[64][40];    // P (relu^2) relayout buffer, wave-private rows
  int wave = threadIdx.x >> 6, lane = threadIdx.x & 63;
  int b = blockIdx.y;
  int i0 = blockIdx.x * 64;
  size_t bo = (size_t)b * NN * CC;
  int m = lane & 15;
  int g4 = lane >> 4;
  int kb = g4 * 8;
  int qrow = i0 + wave * 16 + m;
  short8 aq[8];
#pragma unroll
  for (int ks = 0; ks < 8; ++ks)
    aq[ks] = *(const short8*)(qg + bo + (size_t)qrow * CC + ks * 32 + kb);
  floatx4 vacc[16] = {};
  for (int j0 = 0; j0 < NN; j0 += 32) {
    __syncthreads();
    // stage K tile (row-major, padded)
#pragma unroll
    for (int it = 0; it < 4; ++it) {
      int ci = it * 256 + threadIdx.x;
      int r = ci >> 5;
      int c = (ci & 31) * 8;
      *(short8*)(&Kl[r][c]) = *(const short8*)(kg + bo + (size_t)(j0 + r) * CC + c);
    }
    // stage V tile transposed: Vt[c][swz(j)]
#pragma unroll
    for (int it = 0; it < 4; ++it) {
      int ci = it * 256 + threadIdx.x;
      int jr = ci >> 5;
      int cb = (ci & 31) * 8;
      short8 d = *(const short8*)(vg + bo + (size_t)(j0 + jr) * CC + cb);
      int pos = (((jr >> 3) ^ ((ci & 31) & 3)) << 3) | (jr & 7);
#pragma unroll
      for (int e = 0; e < 8; ++e) Vt[cb + e][pos] = (unsigned short)d[e];
    }
    __syncthreads();
    // S = q @ k^T  (two 16-wide j fragments)
    floatx4 sacc[2] = {};
#pragma unroll
    for (int ks = 0; ks < 8; ++ks) {
#pragma unroll
      for (int f = 0; f < 2; ++f) {
        short8 bk = *(const short8*)(&Kl[f * 16 + m][ks * 32 + kb]);
        sacc[f] = __builtin_amdgcn_mfma_f32_16x16x32_bf16(aq[ks], bk, sacc[f], 0, 0, 0);
      }
    }
    // P = relu(S/n)^2 -> bf16 in wave-private LDS rows
    int pr = wave * 16 + (g4 << 2);
#pragma unroll
    for (int f = 0; f < 2; ++f)
#pragma unroll
      for (int r = 0; r < 4; ++r) {
        float s = fmaxf(sacc[f][r], 0.0f) * (1.0f / NN);
        Pl[pr + r][f * 16 + m] = f2bf(s * s);
      }
    __syncthreads();
    // V += P @ v
    short8 ap = *(const short8*)(&Pl[wave * 16 + m][kb]);
#pragma unroll
    for (int cf = 0; cf < 16; ++cf) {
      int c = cf * 16 + m;
      int pos0 = ((g4 ^ ((c >> 3) & 3)) << 3);
      short8 bv = *(const short8*)(&Vt[c][pos0]);
      vacc[cf] = __builtin_amdgcn_mfma_f32_16x16x32_bf16(ap, bv, vacc[cf], 0, 0, 0);
    }
  }
  // epilogue: multiply by gate, store bf16
  int ob = i0 + wave * 16 + (g4 << 2);
#pragma unroll
  for (int cf = 0; cf < 16; ++cf) {
    int c = cf * 16 + m;
#pragma unroll
    for (int r = 0; r < 4; ++r) {
      size_t off = bo + (size_t)(ob + r) * CC + c;
      og[off] = f2bf(vacc[cf][r] * bf2f(gg[off]));
    }
  }
}

// --------- GEMM5: (V*gate) @ w_proj + b_proj + x -> fp32 out ---------
__global__ __launch_bounds__(256) void gemm_proj(
    const unsigned short* __restrict__ A, const unsigned short* __restrict__ BT,
    const float* __restrict__ bias, const float* __restrict__ xres,
    float* __restrict__ out) {
  int wave = threadIdx.x >> 6, lane = threadIdx.x & 63;
  int m0 = blockIdx.x * 64, n0 = blockIdx.y * 64;
  int m = lane & 15, kb = (lane >> 4) * 8;
  int arow = m0 + wave * 16 + m;
  floatx4 acc[4] = {};
#pragma unroll
  for (int ks = 0; ks < 8; ++ks) {
    short8 a = *(const short8*)(A + (size_t)arow * CC + ks * 32 + kb);
#pragma unroll
    for (int f = 0; f < 4; ++f) {
      short8 bb = *(const short8*)(BT + (size_t)(n0 + f * 16 + m) * CC + ks * 32 + kb);
      acc[f] = __builtin_amdgcn_mfma_f32_16x16x32_bf16(a, bb, acc[f], 0, 0, 0);
    }
  }
  int ob = m0 + wave * 16 + ((lane >> 4) << 2);
#pragma unroll
  for (int f = 0; f < 4; ++f) {
    int col = n0 + f * 16 + m;
    float bv = bias[col];
#pragma unroll
    for (int r = 0; r < 4; ++r) {
      size_t rr = (size_t)(ob + r) * CC;
      out[rr + col] = acc[f][r] + bv + xres[rr + col];
    }
  }
}

extern "C" void kernel_launch(void* const* d_in, const int* in_sizes, int n_in,
                              void* d_out, int out_size, void* d_ws, size_t ws_size,
                              hipStream_t stream) {
  const float* x        = (const float*)d_in[0];
  const float* ln_w     = (const float*)d_in[3];
  const float* ln_b     = (const float*)d_in[4];
  const float* w_hidden = (const float*)d_in[5];
  const float* b_hidden = (const float*)d_in[6];
  const float* w_kv     = (const float*)d_in[7];
  const float* gamma    = (const float*)d_in[8];
  const float* beta     = (const float*)d_in[9];
  const float* w_proj   = (const float*)d_in[10];
  const float* b_proj   = (const float*)d_in[11];
  float* out = (float*)d_out;
  char* ws = (char*)d_ws;

  const size_t SZ = (size_t)BN * CC * 2;  // one bf16 (BN x C) buffer
  unsigned short* normed = (unsigned short*)(ws);
  unsigned short* vbuf   = (unsigned short*)(ws + SZ);
  unsigned short* gbuf   = (unsigned short*)(ws + 2 * SZ);
  unsigned short* qbuf   = (unsigned short*)(ws + 3 * SZ);
  unsigned short* kbuf   = (unsigned short*)(ws + 4 * SZ);
  unsigned short* vgbuf  = normed;  // normed dead after gemm_kv; reuse for V*gate
  unsigned short* wTh    = (unsigned short*)(ws + 5 * SZ);
  unsigned short* wTkv   = (unsigned short*)(ws + 5 * SZ + 512 * 256 * 2);
  unsigned short* wTp    = (unsigned short*)(ws + 5 * SZ + 512 * 256 * 2 + 256 * 256 * 2);

  wconv_kernel<<<512, 256, 0, stream>>>(w_hidden, wTh, 256, 512);
  wconv_kernel<<<256, 256, 0, stream>>>(w_kv, wTkv, 256, 256);
  wconv_kernel<<<256, 256, 0, stream>>>(w_proj, wTp, 256, 256);
  ln_kernel<<<BN / 4, 256, 0, stream>>>(x, ln_w, ln_b, normed);
  gemm_hidden<<<dim3(BN / 64, 8), 256, 0, stream>>>(normed, wTh, b_hidden, vbuf, gbuf);
  gemm_kv<<<dim3(BN / 64, 4), 256, 0, stream>>>(normed, wTkv, gamma, beta, qbuf, kbuf);
  attn_kernel<<<dim3(NN / 64, NB), 256, 0, stream>>>(qbuf, kbuf, vbuf, gbuf, vgbuf);
  gemm_proj<<<dim3(BN / 64, 4), 256, 0, stream>>>(vgbuf, wTp, b_proj, x, out);
}

// Round 2
// 302.224 us; speedup vs baseline: 1.3289x; 1.3289x over previous
//
#include <hip/hip_runtime.h>

#define BN 32768
#define NB 16
#define NN 2048
#define CC 256

using short8  = __attribute__((ext_vector_type(8))) short;
using floatx4 = __attribute__((ext_vector_type(4))) float;

__device__ __forceinline__ unsigned short f2bf(float f) {
  unsigned u = __builtin_bit_cast(unsigned, f);
  u += 0x7fffu + ((u >> 16) & 1u);
  return (unsigned short)(u >> 16);
}
__device__ __forceinline__ float bf2f(unsigned short h) {
  unsigned u = ((unsigned)h) << 16;
  return __builtin_bit_cast(float, u);
}

// ---------------- LayerNorm: one wave per row, bf16 output ----------------
__global__ __launch_bounds__(256) void ln_kernel(
    const float* __restrict__ x, const float* __restrict__ lw,
    const float* __restrict__ lb, unsigned short* __restrict__ normed) {
  int row  = blockIdx.x * 4 + (threadIdx.x >> 6);
  int lane = threadIdx.x & 63;
  float4 v = ((const float4*)(x + (size_t)row * CC))[lane];
  float s  = v.x + v.y + v.z + v.w;
  float s2 = v.x * v.x + v.y * v.y + v.z * v.z + v.w * v.w;
#pragma unroll
  for (int off = 32; off; off >>= 1) {
    s  += __shfl_xor(s, off);
    s2 += __shfl_xor(s2, off);
  }
  float mu = s * (1.0f / CC);
  float rs = rsqrtf(s2 * (1.0f / CC) - mu * mu + 1e-5f);
  float4 w = ((const float4*)lw)[lane];
  float4 b = ((const float4*)lb)[lane];
  ushort4 o;
  o.x = f2bf((v.x - mu) * rs * w.x + b.x);
  o.y = f2bf((v.y - mu) * rs * w.y + b.y);
  o.z = f2bf((v.z - mu) * rs * w.z + b.z);
  o.w = f2bf((v.w - mu) * rs * w.w + b.w);
  ((ushort4*)(normed + (size_t)row * CC))[lane] = o;
}

// ------------- transpose fp32 KxN weight -> bf16 NxK (row-major) -------------
__global__ void wconv_kernel(const float* __restrict__ src,
                             unsigned short* __restrict__ dst, int K, int N) {
  int idx = blockIdx.x * 256 + threadIdx.x;
  if (idx >= K * N) return;
  int n = idx / K, k = idx - n * K;
  dst[idx] = f2bf(src[(size_t)k * N + n]);
}

// --------- GEMM1: normed @ w_hidden + b, silu, split into v / gate ---------
__global__ __launch_bounds__(256) void gemm_hidden(
    const unsigned short* __restrict__ A, const unsigned short* __restrict__ BT,
    const float* __restrict__ bias,
    unsigned short* __restrict__ vout, unsigned short* __restrict__ gout) {
  int wave = threadIdx.x >> 6, lane = threadIdx.x & 63;
  int m0 = blockIdx.x * 64, n0 = blockIdx.y * 64;
  int m = lane & 15, kb = (lane >> 4) * 8;
  int arow = m0 + wave * 16 + m;
  floatx4 acc[4] = {};
#pragma unroll
  for (int ks = 0; ks < 8; ++ks) {
    short8 a = *(const short8*)(A + (size_t)arow * CC + ks * 32 + kb);
#pragma unroll
    for (int f = 0; f < 4; ++f) {
      short8 bb = *(const short8*)(BT + (size_t)(n0 + f * 16 + m) * CC + ks * 32 + kb);
      acc[f] = __builtin_amdgcn_mfma_f32_16x16x32_bf16(a, bb, acc[f], 0, 0, 0);
    }
  }
  int ob = m0 + wave * 16 + ((lane >> 4) << 2);
#pragma unroll
  for (int f = 0; f < 4; ++f) {
    int col = n0 + f * 16 + m;
    float bv = bias[col];
#pragma unroll
    for (int r = 0; r < 4; ++r) {
      float h = acc[f][r] + bv;
      float sv = h / (1.0f + __expf(-h));
      unsigned short hb = f2bf(sv);
      size_t rr = (size_t)(ob + r) * CC;
      if (col < CC) vout[rr + col] = hb;
      else          gout[rr + (col - CC)] = hb;
    }
  }
}

// ----------- GEMM2: normed @ w_kv -> Z; q = Z*g0+b0, k = Z*g1+b1 -----------
__global__ __launch_bounds__(256) void gemm_kv(
    const unsigned short* __restrict__ A, const unsigned short* __restrict__ BT,
    const float* __restrict__ gamma, const float* __restrict__ beta,
    unsigned short* __restrict__ qout, unsigned short* __restrict__ kout) {
  int wave = threadIdx.x >> 6, lane = threadIdx.x & 63;
  int m0 = blockIdx.x * 64, n0 = blockIdx.y * 64;
  int m = lane & 15, kb = (lane >> 4) * 8;
  int arow = m0 + wave * 16 + m;
  floatx4 acc[4] = {};
#pragma unroll
  for (int ks = 0; ks < 8; ++ks) {
    short8 a = *(const short8*)(A + (size_t)arow * CC + ks * 32 + kb);
#pragma unroll
    for (int f = 0; f < 4; ++f) {
      short8 bb = *(const short8*)(BT + (size_t)(n0 + f * 16 + m) * CC + ks * 32 + kb);
      acc[f] = __builtin_amdgcn_mfma_f32_16x16x32_bf16(a, bb, acc[f], 0, 0, 0);
    }
  }
  int ob = m0 + wave * 16 + ((lane >> 4) << 2);
#pragma unroll
  for (int f = 0; f < 4; ++f) {
    int col = n0 + f * 16 + m;
    float g0 = gamma[col], b0 = beta[col];
    float g1 = gamma[CC + col], b1 = beta[CC + col];
#pragma unroll
    for (int r = 0; r < 4; ++r) {
      float z = acc[f][r];
      size_t rr = (size_t)(ob + r) * CC;
      qout[rr + col] = f2bf(z * g0 + b0);
      kout[rr + col] = f2bf(z * g1 + b1);
    }
  }
}

// -------- transpose v: [b][n][c] bf16 -> vT [b][c][n] bf16 (LDS-tiled) --------
__global__ __launch_bounds__(256) void vtrans_kernel(
    const unsigned short* __restrict__ src, unsigned short* __restrict__ dst) {
  __shared__ unsigned short T[64][72];
  int t = threadIdx.x;
  int b = blockIdx.z;
  int n0 = blockIdx.x * 64, c0 = blockIdx.y * 64;
#pragma unroll
  for (int p = 0; p < 2; ++p) {
    int r = p * 32 + (t >> 3), c = (t & 7) * 8;
    *(short8*)(&T[r][c]) = *(const short8*)(src + ((size_t)b * NN + n0 + r) * CC + c0 + c);
  }
  __syncthreads();
#pragma unroll
  for (int p = 0; p < 2; ++p) {
    int cr = p * 32 + (t >> 3), n = (t & 7) * 8;
    short8 o;
#pragma unroll
    for (int e = 0; e < 8; ++e) o[e] = (short)T[n + e][cr];
    *(short8*)(dst + ((size_t)b * CC + c0 + cr) * NN + n0 + n) = o;
  }
}

// ---- fused attention v2: swapped QK, shared P, c-quartered PV ----
// i-tile 64/block (wave w: QK for i-block w), j-tile 32,
// PV: wave w covers c-quarter w x all 4 i-blocks (Vt frag reuse x4).
__global__ __launch_bounds__(256, 2) void attn_kernel(
    const unsigned short* __restrict__ qg, const unsigned short* __restrict__ kg,
    const unsigned short* __restrict__ vT, const unsigned short* __restrict__ gg,
    unsigned short* __restrict__ og) {
  __shared__ unsigned short Kl[32][264];   // K tile row-major, pad 528B (2-way max)
  __shared__ unsigned short Vt[256][40];   // V^T tile, pad 80B (2-way max)
  __shared__ unsigned short Pl[4][16][40]; // P: [i-block][i][j], pad 80B
  const int tid = threadIdx.x;
  const int wave = tid >> 6, lane = tid & 63;
  const int m = lane & 15, g4 = lane >> 4, kb = g4 * 8;
  const int b = blockIdx.y;
  const int i0 = blockIdx.x * 64;
  const size_t bo = (size_t)b * NN * CC;
  // Q fragments for this wave's i-block (held in regs, 32 VGPR)
  short8 aq[8];
#pragma unroll
  for (int ks = 0; ks < 8; ++ks)
    aq[ks] = *(const short8*)(qg + bo + (size_t)(i0 + wave * 16 + m) * CC + ks * 32 + kb);
  floatx4 vacc[4][4] = {};  // [cf][ifb] : c-quarter cols x all i-blocks
  for (int j0 = 0; j0 < NN; j0 += 32) {
    __syncthreads();  // prior tile's reads of Kl/Vt/Pl done
    // stage K rows j0..j0+31 (vectorized, 4 b128/thread)
#pragma unroll
    for (int it = 0; it < 4; ++it) {
      int ci = it * 256 + tid;
      int r = ci >> 5, c = (ci & 31) * 8;
      *(short8*)(&Kl[r][c]) = *(const short8*)(kg + bo + (size_t)(j0 + r) * CC + c);
    }
    // stage V^T tile: rows c=0..255, cols j0..j0+31 (4 b128/thread)
#pragma unroll
    for (int it = 0; it < 4; ++it) {
      int rr = it * 64 + (tid >> 2), seg = (tid & 3) * 8;
      *(short8*)(&Vt[rr][seg]) = *(const short8*)(vT + bo + (size_t)rr * NN + j0 + seg);
    }
    __syncthreads();
    // S^T = K . Q^T  for this wave's i-block: lane holds S^T[j=16jf+4g4+r][i=m]
    floatx4 sacc[2] = {};
#pragma unroll
    for (int ks = 0; ks < 8; ++ks) {
#pragma unroll
      for (int jf = 0; jf < 2; ++jf) {
        short8 ak = *(const short8*)(&Kl[jf * 16 + m][ks * 32 + kb]);
        sacc[jf] = __builtin_amdgcn_mfma_f32_16x16x32_bf16(ak, aq[ks], sacc[jf], 0, 0, 0);
      }
    }
    // P = relu(S/n)^2 -> Pl[wave], packed u32 (j-contiguous per lane)
#pragma unroll
    for (int jf = 0; jf < 2; ++jf)
#pragma unroll
      for (int h = 0; h < 2; ++h) {
        float s0 = fmaxf(sacc[jf][2 * h], 0.0f) * (1.0f / NN);
        float s1 = fmaxf(sacc[jf][2 * h + 1], 0.0f) * (1.0f / NN);
        unsigned u = (unsigned)f2bf(s0 * s0) | ((unsigned)f2bf(s1 * s1) << 16);
        *(unsigned*)(&Pl[wave][m][jf * 16 + g4 * 4 + h * 2]) = u;
      }
    __syncthreads();  // P visible to all waves
    // PV: this wave's c-quarter x all four i-blocks
    short8 ap[4];
#pragma unroll
    for (int ifb = 0; ifb < 4; ++ifb)
      ap[ifb] = *(const short8*)(&Pl[ifb][m][kb]);
#pragma unroll
    for (int cf = 0; cf < 4; ++cf) {
      short8 bv = *(const short8*)(&Vt[wave * 64 + cf * 16 + m][kb]);
#pragma unroll
      for (int ifb = 0; ifb < 4; ++ifb)
        vacc[cf][ifb] = __builtin_amdgcn_mfma_f32_16x16x32_bf16(ap[ifb], bv, vacc[cf][ifb], 0, 0, 0);
    }
  }
  // epilogue: multiply by gate, store bf16
#pragma unroll
  for (int cf = 0; cf < 4; ++cf)
#pragma unroll
    for (int ifb = 0; ifb < 4; ++ifb)
#pragma unroll
      for (int r = 0; r < 4; ++r) {
        int row = i0 + ifb * 16 + g4 * 4 + r;
        int col = wave * 64 + cf * 16 + m;
        size_t off = bo + (size_t)row * CC + col;
        og[off] = f2bf(vacc[cf][ifb][r] * bf2f(gg[off]));
      }
}

// --------- GEMM5: (V*gate) @ w_proj + b_proj + x -> fp32 out ---------
__global__ __launch_bounds__(256) void gemm_proj(
    const unsigned short* __restrict__ A, const unsigned short* __restrict__ BT,
    const float* __restrict__ bias, const float* __restrict__ xres,
    float* __restrict__ out) {
  int wave = threadIdx.x >> 6, lane = threadIdx.x & 63;
  int m0 = blockIdx.x * 64, n0 = blockIdx.y * 64;
  int m = lane & 15, kb = (lane >> 4) * 8;
  int arow = m0 + wave * 16 + m;
  floatx4 acc[4] = {};
#pragma unroll
  for (int ks = 0; ks < 8; ++ks) {
    short8 a = *(const short8*)(A + (size_t)arow * CC + ks * 32 + kb);
#pragma unroll
    for (int f = 0; f < 4; ++f) {
      short8 bb = *(const short8*)(BT + (size_t)(n0 + f * 16 + m) * CC + ks * 32 + kb);
      acc[f] = __builtin_amdgcn_mfma_f32_16x16x32_bf16(a, bb, acc[f], 0, 0, 0);
    }
  }
  int ob = m0 + wave * 16 + ((lane >> 4) << 2);
#pragma unroll
  for (int f = 0; f < 4; ++f) {
    int col = n0 + f * 16 + m;
    float bv = bias[col];
#pragma unroll
    for (int r = 0; r < 4; ++r) {
      size_t rr = (size_t)(ob + r) * CC;
      out[rr + col] = acc[f][r] + bv + xres[rr + col];
    }
  }
}

extern "C" void kernel_launch(void* const* d_in, const int* in_sizes, int n_in,
                              void* d_out, int out_size, void* d_ws, size_t ws_size,
                              hipStream_t stream) {
  const float* x        = (const float*)d_in[0];
  const float* ln_w     = (const float*)d_in[3];
  const float* ln_b     = (const float*)d_in[4];
  const float* w_hidden = (const float*)d_in[5];
  const float* b_hidden = (const float*)d_in[6];
  const float* w_kv     = (const float*)d_in[7];
  const float* gamma    = (const float*)d_in[8];
  const float* beta     = (const float*)d_in[9];
  const float* w_proj   = (const float*)d_in[10];
  const float* b_proj   = (const float*)d_in[11];
  float* out = (float*)d_out;
  char* ws = (char*)d_ws;

  const size_t SZ = (size_t)BN * CC * 2;  // one bf16 (BN x C) buffer
  unsigned short* slot0 = (unsigned short*)(ws);            // normed, later vT
  unsigned short* slot1 = (unsigned short*)(ws + SZ);       // vbuf, later V*gate
  unsigned short* gbuf  = (unsigned short*)(ws + 2 * SZ);
  unsigned short* qbuf  = (unsigned short*)(ws + 3 * SZ);
  unsigned short* kbuf  = (unsigned short*)(ws + 4 * SZ);
  unsigned short* wTh   = (unsigned short*)(ws + 5 * SZ);
  unsigned short* wTkv  = (unsigned short*)(ws + 5 * SZ + 512 * 256 * 2);
  unsigned short* wTp   = (unsigned short*)(ws + 5 * SZ + 512 * 256 * 2 + 256 * 256 * 2);

  wconv_kernel<<<512, 256, 0, stream>>>(w_hidden, wTh, 256, 512);
  wconv_kernel<<<256, 256, 0, stream>>>(w_kv, wTkv, 256, 256);
  wconv_kernel<<<256, 256, 0, stream>>>(w_proj, wTp, 256, 256);
  ln_kernel<<<BN / 4, 256, 0, stream>>>(x, ln_w, ln_b, slot0);
  gemm_hidden<<<dim3(BN / 64, 8), 256, 0, stream>>>(slot0, wTh, b_hidden, slot1, gbuf);
  gemm_kv<<<dim3(BN / 64, 4), 256, 0, stream>>>(slot0, wTkv, gamma, beta, qbuf, kbuf);
  // normed (slot0) dead now -> reuse for vT
  vtrans_kernel<<<dim3(NN / 64, CC / 64, NB), 256, 0, stream>>>(slot1, slot0);
  // attn reads q,k,vT,gate; writes V*gate into slot1 (vbuf dead, V consumed via vT)
  attn_kernel<<<dim3(NN / 64, NB), 256, 0, stream>>>(qbuf, kbuf, slot0, gbuf, slot1);
  gemm_proj<<<dim3(BN / 64, 4), 256, 0, stream>>>(slot1, wTp, b_proj, x, out);
}

// Round 3
// 218.586 us; speedup vs baseline: 1.8374x; 1.3826x over previous
//
#include <hip/hip_runtime.h>

#define BN 32768
#define NB 16
#define NN 2048
#define CC 256

using short8  = __attribute__((ext_vector_type(8))) short;
using floatx4 = __attribute__((ext_vector_type(4))) float;

__device__ __forceinline__ unsigned short f2bf(float f) {
  unsigned u = __builtin_bit_cast(unsigned, f);
  u += 0x7fffu + ((u >> 16) & 1u);
  return (unsigned short)(u >> 16);
}
__device__ __forceinline__ float bf2f(unsigned short h) {
  unsigned u = ((unsigned)h) << 16;
  return __builtin_bit_cast(float, u);
}
__device__ __forceinline__ unsigned char f2fp8(float f) {
  return (unsigned char)(__builtin_amdgcn_cvt_pk_fp8_f32(f, f, 0, false) & 0xff);
}

// ---------------- LayerNorm: one wave per row, bf16 output ----------------
__global__ __launch_bounds__(256) void ln_kernel(
    const float* __restrict__ x, const float* __restrict__ lw,
    const float* __restrict__ lb, unsigned short* __restrict__ normed) {
  int row  = blockIdx.x * 4 + (threadIdx.x >> 6);
  int lane = threadIdx.x & 63;
  float4 v = ((const float4*)(x + (size_t)row * CC))[lane];
  float s  = v.x + v.y + v.z + v.w;
  float s2 = v.x * v.x + v.y * v.y + v.z * v.z + v.w * v.w;
#pragma unroll
  for (int off = 32; off; off >>= 1) {
    s  += __shfl_xor(s, off);
    s2 += __shfl_xor(s2, off);
  }
  float mu = s * (1.0f / CC);
  float rs = rsqrtf(s2 * (1.0f / CC) - mu * mu + 1e-5f);
  float4 w = ((const float4*)lw)[lane];
  float4 b = ((const float4*)lb)[lane];
  ushort4 o;
  o.x = f2bf((v.x - mu) * rs * w.x + b.x);
  o.y = f2bf((v.y - mu) * rs * w.y + b.y);
  o.z = f2bf((v.z - mu) * rs * w.z + b.z);
  o.w = f2bf((v.w - mu) * rs * w.w + b.w);
  ((ushort4*)(normed + (size_t)row * CC))[lane] = o;
}

// ------------- transpose fp32 KxN weight -> bf16 NxK (row-major) -------------
__global__ void wconv_kernel(const float* __restrict__ src,
                             unsigned short* __restrict__ dst, int K, int N) {
  int idx = blockIdx.x * 256 + threadIdx.x;
  if (idx >= K * N) return;
  int n = idx / K, k = idx - n * K;
  dst[idx] = f2bf(src[(size_t)k * N + n]);
}

// --------- GEMM1: normed @ w_hidden + b, silu, split into v / gate ---------
// 128x128 tile, 4 waves, 4x4 fragment blocking
__global__ __launch_bounds__(256) void gemm_hidden(
    const unsigned short* __restrict__ A, const unsigned short* __restrict__ BT,
    const float* __restrict__ bias,
    unsigned short* __restrict__ vout, unsigned short* __restrict__ gout) {
  int wave = threadIdx.x >> 6, lane = threadIdx.x & 63;
  int m = lane & 15, g4 = lane >> 4, kb = g4 * 8;
  int m0 = blockIdx.x * 128 + (wave & 1) * 64;
  int n0 = blockIdx.y * 128 + (wave >> 1) * 64;
  floatx4 acc[4][4] = {};
#pragma unroll
  for (int ks = 0; ks < 8; ++ks) {
    short8 af[4], bf[4];
#pragma unroll
    for (int i = 0; i < 4; ++i)
      af[i] = *(const short8*)(A + (size_t)(m0 + i * 16 + m) * CC + ks * 32 + kb);
#pragma unroll
    for (int j = 0; j < 4; ++j)
      bf[j] = *(const short8*)(BT + (size_t)(n0 + j * 16 + m) * CC + ks * 32 + kb);
#pragma unroll
    for (int i = 0; i < 4; ++i)
#pragma unroll
      for (int j = 0; j < 4; ++j)
        acc[i][j] = __builtin_amdgcn_mfma_f32_16x16x32_bf16(af[i], bf[j], acc[i][j], 0, 0, 0);
  }
#pragma unroll
  for (int j = 0; j < 4; ++j) {
    int col = n0 + j * 16 + m;
    float bv = bias[col];
#pragma unroll
    for (int i = 0; i < 4; ++i)
#pragma unroll
      for (int r = 0; r < 4; ++r) {
        int row = m0 + i * 16 + g4 * 4 + r;
        float h = acc[i][j][r] + bv;
        float sv = h / (1.0f + __expf(-h));
        unsigned short hb = f2bf(sv);
        if (col < CC) vout[(size_t)row * CC + col] = hb;
        else          gout[(size_t)row * CC + col - CC] = hb;
      }
  }
}

// ----------- GEMM2: normed @ w_kv -> Z; q,k fp8 out -----------
__global__ __launch_bounds__(256) void gemm_kv(
    const unsigned short* __restrict__ A, const unsigned short* __restrict__ BT,
    const float* __restrict__ gamma, const float* __restrict__ beta,
    unsigned char* __restrict__ qout, unsigned char* __restrict__ kout) {
  int wave = threadIdx.x >> 6, lane = threadIdx.x & 63;
  int m = lane & 15, g4 = lane >> 4, kb = g4 * 8;
  int m0 = blockIdx.x * 128 + (wave & 1) * 64;
  int n0 = blockIdx.y * 128 + (wave >> 1) * 64;
  floatx4 acc[4][4] = {};
#pragma unroll
  for (int ks = 0; ks < 8; ++ks) {
    short8 af[4], bf[4];
#pragma unroll
    for (int i = 0; i < 4; ++i)
      af[i] = *(const short8*)(A + (size_t)(m0 + i * 16 + m) * CC + ks * 32 + kb);
#pragma unroll
    for (int j = 0; j < 4; ++j)
      bf[j] = *(const short8*)(BT + (size_t)(n0 + j * 16 + m) * CC + ks * 32 + kb);
#pragma unroll
    for (int i = 0; i < 4; ++i)
#pragma unroll
      for (int j = 0; j < 4; ++j)
        acc[i][j] = __builtin_amdgcn_mfma_f32_16x16x32_bf16(af[i], bf[j], acc[i][j], 0, 0, 0);
  }
#pragma unroll
  for (int j = 0; j < 4; ++j) {
    int col = n0 + j * 16 + m;
    float g0 = gamma[col], b0 = beta[col];
    float g1 = gamma[CC + col], b1 = beta[CC + col];
#pragma unroll
    for (int i = 0; i < 4; ++i)
#pragma unroll
      for (int r = 0; r < 4; ++r) {
        int row = m0 + i * 16 + g4 * 4 + r;
        float z = acc[i][j][r];
        qout[(size_t)row * CC + col] = f2fp8(z * g0 + b0);
        kout[(size_t)row * CC + col] = f2fp8(z * g1 + b1);
      }
  }
}

// -- transpose v: [b][n][c] bf16 -> vT blocked fp8 [b][n/32][c][32] --
__global__ __launch_bounds__(256) void vtrans_kernel(
    const unsigned short* __restrict__ src, unsigned char* __restrict__ dst) {
  __shared__ unsigned short T[64][72];
  int t = threadIdx.x;
  int b = blockIdx.z;
  int n0 = blockIdx.x * 64, c0 = blockIdx.y * 64;
#pragma unroll
  for (int p = 0; p < 2; ++p) {
    int r = p * 32 + (t >> 3), c = (t & 7) * 8;
    *(short8*)(&T[r][c]) = *(const short8*)(src + ((size_t)b * NN + n0 + r) * CC + c0 + c);
  }
  __syncthreads();
#pragma unroll
  for (int p = 0; p < 2; ++p) {
    int cr = p * 32 + (t >> 3), jn = (t & 7) * 8;
    float f[8];
#pragma unroll
    for (int e = 0; e < 8; ++e) f[e] = bf2f(T[jn + e][cr]);
    unsigned u0 = __builtin_amdgcn_cvt_pk_fp8_f32(f[2], f[3], 0, true);
    u0 = __builtin_amdgcn_cvt_pk_fp8_f32(f[0], f[1], (int)u0, false);
    unsigned u1 = __builtin_amdgcn_cvt_pk_fp8_f32(f[6], f[7], 0, true);
    u1 = __builtin_amdgcn_cvt_pk_fp8_f32(f[4], f[5], (int)u1, false);
    int jt = (n0 + jn) >> 5, jo = jn & 31;
    size_t addr = (((size_t)b * (NN / 32) + jt) * CC + (c0 + cr)) * 32 + jo;
    uint2 d; d.x = u0; d.y = u1;
    *(uint2*)(dst + addr) = d;
  }
}

// ---- fused attention v3: fp8, swapped QK (i-span 32 / j-span 16 per wave),
//      shared P (fp8, x2^14), c-quartered PV ----
__global__ __launch_bounds__(256, 2) void attn_kernel(
    const unsigned char* __restrict__ qg, const unsigned char* __restrict__ kg,
    const unsigned char* __restrict__ vTb, const unsigned short* __restrict__ gg,
    unsigned short* __restrict__ og) {
  __shared__ unsigned char Kl[32][272];   // K tile fp8, 272B rows
  __shared__ unsigned char Vt[256][48];   // V^T tile fp8, 48B rows
  __shared__ unsigned char Pl[4][16][40]; // P' fp8: [i-block][i][j], 40B rows
  const int tid = threadIdx.x;
  const int wave = tid >> 6, lane = tid & 63;
  const int m = lane & 15, g4 = lane >> 4;
  const int ih = wave & 1, jh = wave >> 1;
  const int b = blockIdx.y;
  const int i0 = blockIdx.x * 64;
  const size_t bo = (size_t)b * NN * CC;
  // Q fragments: 2 i-blocks x 8 ks, 8B each (fp8)
  uint2 qf[2][8];
#pragma unroll
  for (int ib = 0; ib < 2; ++ib)
#pragma unroll
    for (int ks = 0; ks < 8; ++ks)
      qf[ib][ks] = *(const uint2*)(qg + bo + (size_t)(i0 + ih * 32 + ib * 16 + m) * CC + ks * 32 + g4 * 8);
  floatx4 vacc[4][4] = {};  // [cf][ifb]
  for (int j0 = 0; j0 < NN; j0 += 32) {
    __syncthreads();
    // stage K tile: thread t -> row t>>3, 32B at col (t&7)*32
    {
      int r = tid >> 3, cb = (tid & 7) * 32;
      const unsigned char* kp = kg + bo + (size_t)(j0 + r) * CC + cb;
      *(uint4*)(&Kl[r][cb])      = *(const uint4*)(kp);
      *(uint4*)(&Kl[r][cb + 16]) = *(const uint4*)(kp + 16);
    }
    // stage V^T tile: thread t -> row c=t, 32B (contiguous global block)
    {
      size_t src = (((size_t)b * (NN / 32) + (j0 >> 5)) * CC + tid) * 32;
      uint4 e0 = *(const uint4*)(vTb + src);
      uint4 e1 = *(const uint4*)(vTb + src + 16);
      uint2 d[4];
      d[0].x = e0.x; d[0].y = e0.y; d[1].x = e0.z; d[1].y = e0.w;
      d[2].x = e1.x; d[2].y = e1.y; d[3].x = e1.z; d[3].y = e1.w;
      int rot = (tid >> 3) & 3;
#pragma unroll
      for (int s = 0; s < 4; ++s) {
        int c = (s + rot) & 3;
        *(uint2*)(&Vt[tid][c * 8]) = d[c];
      }
    }
    __syncthreads();
    // S^T = K . Q^T for (i-half ih, j-half jh): lane holds S^T[jh*16+4g4+r][m of i-block]
    floatx4 sacc[2] = {};
#pragma unroll
    for (int ks = 0; ks < 8; ++ks) {
      long ak = __builtin_bit_cast(long, *(const uint2*)(&Kl[jh * 16 + m][ks * 32 + g4 * 8]));
#pragma unroll
      for (int ib = 0; ib < 2; ++ib)
        sacc[ib] = __builtin_amdgcn_mfma_f32_16x16x32_fp8_fp8(
            ak, __builtin_bit_cast(long, qf[ib][ks]), sacc[ib], 0, 0, 0);
    }
    // P' = (relu(S)/16)^2  (= (relu(S)/n)^2 * 2^14), fp8, packed u32 write
#pragma unroll
    for (int ib = 0; ib < 2; ++ib) {
      float p[4];
#pragma unroll
      for (int r = 0; r < 4; ++r) {
        float s = fmaxf(sacc[ib][r], 0.0f) * 0.0625f;
        p[r] = s * s;
      }
      unsigned u = __builtin_amdgcn_cvt_pk_fp8_f32(p[2], p[3], 0, true);
      u = __builtin_amdgcn_cvt_pk_fp8_f32(p[0], p[1], (int)u, false);
      *(unsigned*)(&Pl[ih * 2 + ib][m][jh * 16 + g4 * 4]) = u;
    }
    __syncthreads();
    // PV: wave's c-quarter (64 cols) x all 4 i-blocks
    long ap[4];
#pragma unroll
    for (int ifb = 0; ifb < 4; ++ifb)
      ap[ifb] = __builtin_bit_cast(long, *(const uint2*)(&Pl[ifb][m][g4 * 8]));
#pragma unroll
    for (int cf = 0; cf < 4; ++cf) {
      long bv = __builtin_bit_cast(long, *(const uint2*)(&Vt[wave * 64 + cf * 16 + m][g4 * 8]));
#pragma unroll
      for (int ifb = 0; ifb < 4; ++ifb)
        vacc[cf][ifb] = __builtin_amdgcn_mfma_f32_16x16x32_fp8_fp8(ap[ifb], bv, vacc[cf][ifb], 0, 0, 0);
    }
  }
  // epilogue: scale back 2^-14, multiply by gate, store bf16
  const float sc = 1.0f / 16384.0f;
#pragma unroll
  for (int cf = 0; cf < 4; ++cf)
#pragma unroll
    for (int ifb = 0; ifb < 4; ++ifb)
#pragma unroll
      for (int r = 0; r < 4; ++r) {
        int row = i0 + ifb * 16 + g4 * 4 + r;
        int col = wave * 64 + cf * 16 + m;
        size_t off = bo + (size_t)row * CC + col;
        og[off] = f2bf(vacc[cf][ifb][r] * sc * bf2f(gg[off]));
      }
}

// --------- GEMM5: (V*gate) @ w_proj + b_proj + x -> fp32 out ---------
__global__ __launch_bounds__(256) void gemm_proj(
    const unsigned short* __restrict__ A, const unsigned short* __restrict__ BT,
    const float* __restrict__ bias, const float* __restrict__ xres,
    float* __restrict__ out) {
  int wave = threadIdx.x >> 6, lane = threadIdx.x & 63;
  int m = lane & 15, g4 = lane >> 4, kb = g4 * 8;
  int m0 = blockIdx.x * 128 + (wave & 1) * 64;
  int n0 = blockIdx.y * 128 + (wave >> 1) * 64;
  floatx4 acc[4][4] = {};
#pragma unroll
  for (int ks = 0; ks < 8; ++ks) {
    short8 af[4], bf[4];
#pragma unroll
    for (int i = 0; i < 4; ++i)
      af[i] = *(const short8*)(A + (size_t)(m0 + i * 16 + m) * CC + ks * 32 + kb);
#pragma unroll
    for (int j = 0; j < 4; ++j)
      bf[j] = *(const short8*)(BT + (size_t)(n0 + j * 16 + m) * CC + ks * 32 + kb);
#pragma unroll
    for (int i = 0; i < 4; ++i)
#pragma unroll
      for (int j = 0; j < 4; ++j)
        acc[i][j] = __builtin_amdgcn_mfma_f32_16x16x32_bf16(af[i], bf[j], acc[i][j], 0, 0, 0);
  }
#pragma unroll
  for (int j = 0; j < 4; ++j) {
    int col = n0 + j * 16 + m;
    float bv = bias[col];
#pragma unroll
    for (int i = 0; i < 4; ++i)
#pragma unroll
      for (int r = 0; r < 4; ++r) {
        int row = m0 + i * 16 + g4 * 4 + r;
        size_t rr = (size_t)row * CC;
        out[rr + col] = acc[i][j][r] + bv + xres[rr + col];
      }
  }
}

extern "C" void kernel_launch(void* const* d_in, const int* in_sizes, int n_in,
                              void* d_out, int out_size, void* d_ws, size_t ws_size,
                              hipStream_t stream) {
  const float* x        = (const float*)d_in[0];
  const float* ln_w     = (const float*)d_in[3];
  const float* ln_b     = (const float*)d_in[4];
  const float* w_hidden = (const float*)d_in[5];
  const float* b_hidden = (const float*)d_in[6];
  const float* w_kv     = (const float*)d_in[7];
  const float* gamma    = (const float*)d_in[8];
  const float* beta     = (const float*)d_in[9];
  const float* w_proj   = (const float*)d_in[10];
  const float* b_proj   = (const float*)d_in[11];
  float* out = (float*)d_out;
  char* ws = (char*)d_ws;

  const size_t SZ = (size_t)BN * CC * 2;  // one bf16 (BN x C) buffer (bytes)
  const size_t HZ = SZ / 2;               // one fp8 buffer
  unsigned short* normed = (unsigned short*)(ws);
  unsigned short* vbuf   = (unsigned short*)(ws + SZ);      // v bf16; later attn out
  unsigned short* gbuf   = (unsigned short*)(ws + 2 * SZ);
  unsigned char*  qbuf   = (unsigned char*)(ws + 3 * SZ);
  unsigned char*  kbuf   = (unsigned char*)(ws + 3 * SZ + HZ);
  unsigned char*  vTb    = (unsigned char*)(ws + 3 * SZ + 2 * HZ);
  unsigned short* wTh    = (unsigned short*)(ws + 3 * SZ + 3 * HZ);
  unsigned short* wTkv   = (unsigned short*)(ws + 3 * SZ + 3 * HZ + 512 * 256 * 2);
  unsigned short* wTp    = (unsigned short*)(ws + 3 * SZ + 3 * HZ + 512 * 256 * 2 + 256 * 256 * 2);

  wconv_kernel<<<512, 256, 0, stream>>>(w_hidden, wTh, 256, 512);
  wconv_kernel<<<256, 256, 0, stream>>>(w_kv, wTkv, 256, 256);
  wconv_kernel<<<256, 256, 0, stream>>>(w_proj, wTp, 256, 256);
  ln_kernel<<<BN / 4, 256, 0, stream>>>(x, ln_w, ln_b, normed);
  gemm_hidden<<<dim3(BN / 128, 4), 256, 0, stream>>>(normed, wTh, b_hidden, vbuf, gbuf);
  gemm_kv<<<dim3(BN / 128, 2), 256, 0, stream>>>(normed, wTkv, gamma, beta, qbuf, kbuf);
  vtrans_kernel<<<dim3(NN / 64, CC / 64, NB), 256, 0, stream>>>(vbuf, vTb);
  // attn reads q,k,vT,gate; writes V*gate (bf16) into vbuf (v dead after vtrans)
  attn_kernel<<<dim3(NN / 64, NB), 256, 0, stream>>>(qbuf, kbuf, vTb, gbuf, vbuf);
  gemm_proj<<<dim3(BN / 128, 2), 256, 0, stream>>>(vbuf, wTp, b_proj, x, out);
}

// Round 4
// 185.984 us; speedup vs baseline: 2.1595x; 1.1753x over previous
//
#include <hip/hip_runtime.h>

#define BN 32768
#define NB 16
#define NN 2048
#define CC 256
#define JT 64
#define NTILES (NN / JT)

using short8  = __attribute__((ext_vector_type(8))) short;
using floatx4 = __attribute__((ext_vector_type(4))) float;

__device__ __forceinline__ unsigned short f2bf(float f) {
  unsigned u = __builtin_bit_cast(unsigned, f);
  u += 0x7fffu + ((u >> 16) & 1u);
  return (unsigned short)(u >> 16);
}
__device__ __forceinline__ float bf2f(unsigned short h) {
  unsigned u = ((unsigned)h) << 16;
  return __builtin_bit_cast(float, u);
}
__device__ __forceinline__ unsigned char f2fp8(float f) {
  return (unsigned char)(__builtin_amdgcn_cvt_pk_fp8_f32(f, f, 0, false) & 0xff);
}
__device__ __forceinline__ void gll16(const void* g, void* l) {
  __builtin_amdgcn_global_load_lds(
      (const __attribute__((address_space(1))) void*)g,
      (__attribute__((address_space(3))) void*)l, 16, 0, 0);
}

// ---------------- LayerNorm: one wave per row, bf16 output ----------------
__global__ __launch_bounds__(256) void ln_kernel(
    const float* __restrict__ x, const float* __restrict__ lw,
    const float* __restrict__ lb, unsigned short* __restrict__ normed) {
  int row  = blockIdx.x * 4 + (threadIdx.x >> 6);
  int lane = threadIdx.x & 63;
  float4 v = ((const float4*)(x + (size_t)row * CC))[lane];
  float s  = v.x + v.y + v.z + v.w;
  float s2 = v.x * v.x + v.y * v.y + v.z * v.z + v.w * v.w;
#pragma unroll
  for (int off = 32; off; off >>= 1) {
    s  += __shfl_xor(s, off);
    s2 += __shfl_xor(s2, off);
  }
  float mu = s * (1.0f / CC);
  float rs = rsqrtf(s2 * (1.0f / CC) - mu * mu + 1e-5f);
  float4 w = ((const float4*)lw)[lane];
  float4 b = ((const float4*)lb)[lane];
  ushort4 o;
  o.x = f2bf((v.x - mu) * rs * w.x + b.x);
  o.y = f2bf((v.y - mu) * rs * w.y + b.y);
  o.z = f2bf((v.z - mu) * rs * w.z + b.z);
  o.w = f2bf((v.w - mu) * rs * w.w + b.w);
  ((ushort4*)(normed + (size_t)row * CC))[lane] = o;
}

// ------------- transpose fp32 KxN weight -> bf16 NxK (row-major) -------------
__global__ void wconv_kernel(const float* __restrict__ src,
                             unsigned short* __restrict__ dst, int K, int N) {
  int idx = blockIdx.x * 256 + threadIdx.x;
  if (idx >= K * N) return;
  int n = idx / K, k = idx - n * K;
  dst[idx] = f2bf(src[(size_t)k * N + n]);
}

// --------- GEMM1: normed @ w_hidden + b, silu, split into v / gate ---------
__global__ __launch_bounds__(256) void gemm_hidden(
    const unsigned short* __restrict__ A, const unsigned short* __restrict__ BT,
    const float* __restrict__ bias,
    unsigned short* __restrict__ vout, unsigned short* __restrict__ gout) {
  int wave = threadIdx.x >> 6, lane = threadIdx.x & 63;
  int m = lane & 15, g4 = lane >> 4, kb = g4 * 8;
  int m0 = blockIdx.x * 128 + (wave & 1) * 64;
  int n0 = blockIdx.y * 128 + (wave >> 1) * 64;
  floatx4 acc[4][4] = {};
#pragma unroll
  for (int ks = 0; ks < 8; ++ks) {
    short8 af[4], bf[4];
#pragma unroll
    for (int i = 0; i < 4; ++i)
      af[i] = *(const short8*)(A + (size_t)(m0 + i * 16 + m) * CC + ks * 32 + kb);
#pragma unroll
    for (int j = 0; j < 4; ++j)
      bf[j] = *(const short8*)(BT + (size_t)(n0 + j * 16 + m) * CC + ks * 32 + kb);
#pragma unroll
    for (int i = 0; i < 4; ++i)
#pragma unroll
      for (int j = 0; j < 4; ++j)
        acc[i][j] = __builtin_amdgcn_mfma_f32_16x16x32_bf16(af[i], bf[j], acc[i][j], 0, 0, 0);
  }
#pragma unroll
  for (int j = 0; j < 4; ++j) {
    int col = n0 + j * 16 + m;
    float bv = bias[col];
#pragma unroll
    for (int i = 0; i < 4; ++i)
#pragma unroll
      for (int r = 0; r < 4; ++r) {
        int row = m0 + i * 16 + g4 * 4 + r;
        float h = acc[i][j][r] + bv;
        float sv = h / (1.0f + __expf(-h));
        unsigned short hb = f2bf(sv);
        if (col < CC) vout[(size_t)row * CC + col] = hb;
        else          gout[(size_t)row * CC + col - CC] = hb;
      }
  }
}

// ----------- GEMM2: normed @ w_kv -> Z; q,k fp8 out -----------
__global__ __launch_bounds__(256) void gemm_kv(
    const unsigned short* __restrict__ A, const unsigned short* __restrict__ BT,
    const float* __restrict__ gamma, const float* __restrict__ beta,
    unsigned char* __restrict__ qout, unsigned char* __restrict__ kout) {
  int wave = threadIdx.x >> 6, lane = threadIdx.x & 63;
  int m = lane & 15, g4 = lane >> 4, kb = g4 * 8;
  int m0 = blockIdx.x * 128 + (wave & 1) * 64;
  int n0 = blockIdx.y * 128 + (wave >> 1) * 64;
  floatx4 acc[4][4] = {};
#pragma unroll
  for (int ks = 0; ks < 8; ++ks) {
    short8 af[4], bf[4];
#pragma unroll
    for (int i = 0; i < 4; ++i)
      af[i] = *(const short8*)(A + (size_t)(m0 + i * 16 + m) * CC + ks * 32 + kb);
#pragma unroll
    for (int j = 0; j < 4; ++j)
      bf[j] = *(const short8*)(BT + (size_t)(n0 + j * 16 + m) * CC + ks * 32 + kb);
#pragma unroll
    for (int i = 0; i < 4; ++i)
#pragma unroll
      for (int j = 0; j < 4; ++j)
        acc[i][j] = __builtin_amdgcn_mfma_f32_16x16x32_bf16(af[i], bf[j], acc[i][j], 0, 0, 0);
  }
#pragma unroll
  for (int j = 0; j < 4; ++j) {
    int col = n0 + j * 16 + m;
    float g0 = gamma[col], b0 = beta[col];
    float g1 = gamma[CC + col], b1 = beta[CC + col];
#pragma unroll
    for (int i = 0; i < 4; ++i)
#pragma unroll
      for (int r = 0; r < 4; ++r) {
        int row = m0 + i * 16 + g4 * 4 + r;
        float z = acc[i][j][r];
        qout[(size_t)row * CC + col] = f2fp8(z * g0 + b0);
        kout[(size_t)row * CC + col] = f2fp8(z * g1 + b1);
      }
  }
}

// -- transpose v: [b][n][c] bf16 -> vT blocked fp8 [b][n/32][c][32] --
__global__ __launch_bounds__(256) void vtrans_kernel(
    const unsigned short* __restrict__ src, unsigned char* __restrict__ dst) {
  __shared__ unsigned short T[64][72];
  int t = threadIdx.x;
  int b = blockIdx.z;
  int n0 = blockIdx.x * 64, c0 = blockIdx.y * 64;
#pragma unroll
  for (int p = 0; p < 2; ++p) {
    int r = p * 32 + (t >> 3), c = (t & 7) * 8;
    *(short8*)(&T[r][c]) = *(const short8*)(src + ((size_t)b * NN + n0 + r) * CC + c0 + c);
  }
  __syncthreads();
#pragma unroll
  for (int p = 0; p < 2; ++p) {
    int cr = p * 32 + (t >> 3), jn = (t & 7) * 8;
    float f[8];
#pragma unroll
    for (int e = 0; e < 8; ++e) f[e] = bf2f(T[jn + e][cr]);
    unsigned u0 = __builtin_amdgcn_cvt_pk_fp8_f32(f[2], f[3], 0, true);
    u0 = __builtin_amdgcn_cvt_pk_fp8_f32(f[0], f[1], (int)u0, false);
    unsigned u1 = __builtin_amdgcn_cvt_pk_fp8_f32(f[6], f[7], 0, true);
    u1 = __builtin_amdgcn_cvt_pk_fp8_f32(f[4], f[5], (int)u1, false);
    int jt = (n0 + jn) >> 5, jo = jn & 31;
    size_t addr = (((size_t)b * (NN / 32) + jt) * CC + (c0 + cr)) * 32 + jo;
    uint2 d; d.x = u0; d.y = u1;
    *(uint2*)(dst + addr) = d;
  }
}

// ---- fused attention v4: fp8, j-tile 64, double-buffered global_load_lds
//      staging with XOR-swizzled linear LDS, 2 barriers/tile ----
__global__ __launch_bounds__(256, 2) void attn_kernel(
    const unsigned char* __restrict__ qg, const unsigned char* __restrict__ kg,
    const unsigned char* __restrict__ vTb, const unsigned short* __restrict__ gg,
    unsigned short* __restrict__ og) {
  __shared__ unsigned char Kl[2][64][256];   // 16B-slot swizzle: slot ^= (row&15)
  __shared__ unsigned char Vt[2][256][64];   // 16B-slot swizzle: slot ^= (c&3)
  __shared__ unsigned char Pl[4][16][72];    // P' fp8, padded rows
  const int tid = threadIdx.x;
  const int wave = tid >> 6, lane = tid & 63;
  const int m = lane & 15, g4 = lane >> 4;
  const int ih = wave & 1, jh = wave >> 1;
  const int b = blockIdx.y;
  const int i0 = blockIdx.x * 64;
  const size_t bo = (size_t)b * NN * CC;
  const unsigned char* kg_b  = kg + bo;
  const unsigned char* vT_b  = vTb + bo;

  // Q fragments: 2 i-blocks x 8 ks, 8B each (fp8)
  uint2 qf[2][8];
#pragma unroll
  for (int ib = 0; ib < 2; ++ib)
#pragma unroll
    for (int ks = 0; ks < 8; ++ks)
      qf[ib][ks] = *(const uint2*)(qg + bo + (size_t)(i0 + ih * 32 + ib * 16 + m) * CC + ks * 32 + g4 * 8);

  floatx4 vacc[4][4] = {};  // [cf][ifb]

  // ---- staging: K tile (64x256B) + V tile (256x64B) via global_load_lds ----
  auto stage = [&](int buf, int jt) {
#pragma unroll
    for (int s = 0; s < 4; ++s) {
      int row = s * 16 + wave * 4 + (lane >> 4);
      int colg = ((lane & 15) ^ (row & 15)) * 16;
      gll16(kg_b + (size_t)(jt * JT + row) * CC + colg,
            &Kl[buf][0][0] + s * 4096 + wave * 1024);
    }
#pragma unroll
    for (int s = 0; s < 4; ++s) {
      int c = s * 64 + wave * 16 + (lane >> 2);
      int gslot = (lane & 3) ^ (c & 3);
      gll16(vT_b + ((size_t)(2 * jt + (gslot >> 1)) * CC + c) * 32 + (gslot & 1) * 16,
            &Vt[buf][0][0] + s * 4096 + wave * 1024);
    }
  };

  stage(0, 0);
  for (int t = 0; t < NTILES; ++t) {
    const int cur = t & 1;
    __syncthreads();  // tile-t stage landed (vmcnt drain); prior PV reads done
    if (t + 1 < NTILES) stage(cur ^ 1, t + 1);
    // ---- QK: S^T = K . Q^T ; lane holds S^T[j][i=m] ----
    floatx4 sacc[2][2] = {};  // [jf][ib]
#pragma unroll
    for (int ks = 0; ks < 8; ++ks) {
      long ak[2];
#pragma unroll
      for (int jf = 0; jf < 2; ++jf) {
        int row = jh * 32 + jf * 16 + m;
        int sl = (ks * 2 + (g4 >> 1)) ^ m;
        ak[jf] = *(const long*)(&Kl[cur][0][0] + row * 256 + sl * 16 + (g4 & 1) * 8);
      }
#pragma unroll
      for (int jf = 0; jf < 2; ++jf)
#pragma unroll
        for (int ib = 0; ib < 2; ++ib)
          sacc[jf][ib] = __builtin_amdgcn_mfma_f32_16x16x32_fp8_fp8(
              ak[jf], __builtin_bit_cast(long, qf[ib][ks]), sacc[jf][ib], 0, 0, 0);
    }
    // ---- P' = (relu(S)/16)^2, fp8, packed u32 ----
#pragma unroll
    for (int jf = 0; jf < 2; ++jf)
#pragma unroll
      for (int ib = 0; ib < 2; ++ib) {
        float p[4];
#pragma unroll
        for (int r = 0; r < 4; ++r) {
          float s = fmaxf(sacc[jf][ib][r], 0.0f) * 0.0625f;
          p[r] = s * s;
        }
        unsigned u = __builtin_amdgcn_cvt_pk_fp8_f32(p[2], p[3], 0, true);
        u = __builtin_amdgcn_cvt_pk_fp8_f32(p[0], p[1], (int)u, false);
        *(unsigned*)(&Pl[ih * 2 + ib][m][jh * 32 + jf * 16 + g4 * 4]) = u;
      }
    __syncthreads();  // P visible; also drains t+1 stage loads
    // ---- PV: wave's c-quarter x 4 i-blocks x 2 k-steps ----
    long ap[4][2];
#pragma unroll
    for (int ifb = 0; ifb < 4; ++ifb)
#pragma unroll
      for (int kk = 0; kk < 2; ++kk)
        ap[ifb][kk] = *(const long*)(&Pl[ifb][m][kk * 32 + g4 * 8]);
#pragma unroll
    for (int kk = 0; kk < 2; ++kk)
#pragma unroll
      for (int cf = 0; cf < 4; ++cf) {
        int c = wave * 64 + cf * 16 + m;
        int sl = (kk * 2 + (g4 >> 1)) ^ (c & 3);
        long bv = *(const long*)(&Vt[cur][0][0] + c * 64 + sl * 16 + (g4 & 1) * 8);
#pragma unroll
        for (int ifb = 0; ifb < 4; ++ifb)
          vacc[cf][ifb] = __builtin_amdgcn_mfma_f32_16x16x32_fp8_fp8(
              ap[ifb][kk], bv, vacc[cf][ifb], 0, 0, 0);
      }
  }
  // epilogue: scale back 2^-14, multiply by gate, store bf16
  const float sc = 1.0f / 16384.0f;
#pragma unroll
  for (int cf = 0; cf < 4; ++cf)
#pragma unroll
    for (int ifb = 0; ifb < 4; ++ifb)
#pragma unroll
      for (int r = 0; r < 4; ++r) {
        int row = i0 + ifb * 16 + g4 * 4 + r;
        int col = wave * 64 + cf * 16 + m;
        size_t off = bo + (size_t)row * CC + col;
        og[off] = f2bf(vacc[cf][ifb][r] * sc * bf2f(gg[off]));
      }
}

// --------- GEMM5: (V*gate) @ w_proj + b_proj + x -> fp32 out ---------
__global__ __launch_bounds__(256) void gemm_proj(
    const unsigned short* __restrict__ A, const unsigned short* __restrict__ BT,
    const float* __restrict__ bias, const float* __restrict__ xres,
    float* __restrict__ out) {
  int wave = threadIdx.x >> 6, lane = threadIdx.x & 63;
  int m = lane & 15, g4 = lane >> 4, kb = g4 * 8;
  int m0 = blockIdx.x * 128 + (wave & 1) * 64;
  int n0 = blockIdx.y * 128 + (wave >> 1) * 64;
  floatx4 acc[4][4] = {};
#pragma unroll
  for (int ks = 0; ks < 8; ++ks) {
    short8 af[4], bf[4];
#pragma unroll
    for (int i = 0; i < 4; ++i)
      af[i] = *(const short8*)(A + (size_t)(m0 + i * 16 + m) * CC + ks * 32 + kb);
#pragma unroll
    for (int j = 0; j < 4; ++j)
      bf[j] = *(const short8*)(BT + (size_t)(n0 + j * 16 + m) * CC + ks * 32 + kb);
#pragma unroll
    for (int i = 0; i < 4; ++i)
#pragma unroll
      for (int j = 0; j < 4; ++j)
        acc[i][j] = __builtin_amdgcn_mfma_f32_16x16x32_bf16(af[i], bf[j], acc[i][j], 0, 0, 0);
  }
#pragma unroll
  for (int j = 0; j < 4; ++j) {
    int col = n0 + j * 16 + m;
    float bv = bias[col];
#pragma unroll
    for (int i = 0; i < 4; ++i)
#pragma unroll
      for (int r = 0; r < 4; ++r) {
        int row = m0 + i * 16 + g4 * 4 + r;
        size_t rr = (size_t)row * CC;
        out[rr + col] = acc[i][j][r] + bv + xres[rr + col];
      }
  }
}

extern "C" void kernel_launch(void* const* d_in, const int* in_sizes, int n_in,
                              void* d_out, int out_size, void* d_ws, size_t ws_size,
                              hipStream_t stream) {
  const float* x        = (const float*)d_in[0];
  const float* ln_w     = (const float*)d_in[3];
  const float* ln_b     = (const float*)d_in[4];
  const float* w_hidden = (const float*)d_in[5];
  const float* b_hidden = (const float*)d_in[6];
  const float* w_kv     = (const float*)d_in[7];
  const float* gamma    = (const float*)d_in[8];
  const float* beta     = (const float*)d_in[9];
  const float* w_proj   = (const float*)d_in[10];
  const float* b_proj   = (const float*)d_in[11];
  float* out = (float*)d_out;
  char* ws = (char*)d_ws;

  const size_t SZ = (size_t)BN * CC * 2;  // one bf16 (BN x C) buffer (bytes)
  const size_t HZ = SZ / 2;               // one fp8 buffer
  unsigned short* normed = (unsigned short*)(ws);
  unsigned short* vbuf   = (unsigned short*)(ws + SZ);      // v bf16; later attn out
  unsigned short* gbuf   = (unsigned short*)(ws + 2 * SZ);
  unsigned char*  qbuf   = (unsigned char*)(ws + 3 * SZ);
  unsigned char*  kbuf   = (unsigned char*)(ws + 3 * SZ + HZ);
  unsigned char*  vTb    = (unsigned char*)(ws + 3 * SZ + 2 * HZ);
  unsigned short* wTh    = (unsigned short*)(ws + 3 * SZ + 3 * HZ);
  unsigned short* wTkv   = (unsigned short*)(ws + 3 * SZ + 3 * HZ + 512 * 256 * 2);
  unsigned short* wTp    = (unsigned short*)(ws + 3 * SZ + 3 * HZ + 512 * 256 * 2 + 256 * 256 * 2);

  wconv_kernel<<<512, 256, 0, stream>>>(w_hidden, wTh, 256, 512);
  wconv_kernel<<<256, 256, 0, stream>>>(w_kv, wTkv, 256, 256);
  wconv_kernel<<<256, 256, 0, stream>>>(w_proj, wTp, 256, 256);
  ln_kernel<<<BN / 4, 256, 0, stream>>>(x, ln_w, ln_b, normed);
  gemm_hidden<<<dim3(BN / 128, 4), 256, 0, stream>>>(normed, wTh, b_hidden, vbuf, gbuf);
  gemm_kv<<<dim3(BN / 128, 2), 256, 0, stream>>>(normed, wTkv, gamma, beta, qbuf, kbuf);
  vtrans_kernel<<<dim3(NN / 64, CC / 64, NB), 256, 0, stream>>>(vbuf, vTb);
  attn_kernel<<<dim3(NN / 64, NB), 256, 0, stream>>>(qbuf, kbuf, vTb, gbuf, vbuf);
  gemm_proj<<<dim3(BN / 128, 2), 256, 0, stream>>>(vbuf, wTp, b_proj, x, out);
}